// Round 5
// baseline (1774.437 us; speedup 1.0000x reference)
//
#include <hip/hip_runtime.h>
#include <hip/hip_bf16.h>

#define N_USERS   50000
#define N_ITEMS   100000
#define N_NODES   150000
#define DIM       64
#define N_INTENTS 128
#define N_EDGES   3000000
#define BSHIFT    5                       // 32 rows per bucket
#define NBUCK     ((N_NODES + 31) >> BSHIFT)

static __device__ __forceinline__ float wsum64(float v){
#pragma unroll
  for (int m = 32; m >= 1; m >>= 1) v += __shfl_xor(v, m, 64);
  return v;
}
static __device__ __forceinline__ float wmax64(float v){
#pragma unroll
  for (int m = 32; m >= 1; m >>= 1) v = fmaxf(v, __shfl_xor(v, m, 64));
  return v;
}

// ---- DPP 16-lane row reduction (full-rate VALU)
template<int CTRL>
static __device__ __forceinline__ float dpp_ror_add(float x){
  int t = __builtin_amdgcn_update_dpp(0, __builtin_bit_cast(int, x),
                                      CTRL, 0xF, 0xF, true);
  return x + __builtin_bit_cast(float, t);
}
static __device__ __forceinline__ float row16_allsum(float x){
  x = dpp_ror_add<0x128>(x);  // row_ror:8
  x = dpp_ror_add<0x124>(x);  // row_ror:4
  x = dpp_ror_add<0x122>(x);  // row_ror:2
  x = dpp_ror_add<0x121>(x);  // row_ror:1
  return x;
}

// bf16 pack/unpack
static __device__ __forceinline__ unsigned short f2bf(float x){
  __hip_bfloat16 h = __float2bfloat16(x);
  return __builtin_bit_cast(unsigned short, h);
}
static __device__ __forceinline__ float bf_lo(unsigned int v){
  return __builtin_bit_cast(float, v << 16);
}
static __device__ __forceinline__ float bf_hi(unsigned int v){
  return __builtin_bit_cast(float, v & 0xFFFF0000u);
}

// emb = concat(user_emb, item_emb); acc(=d_out) = emb
__global__ void k_init(const float* __restrict__ ue, const float* __restrict__ ie,
                       float* __restrict__ emb, float* __restrict__ acc){
  int i = blockIdx.x * 256 + threadIdx.x;
  if (i >= N_NODES * DIM) return;
  float v = (i < N_USERS * DIM) ? ue[i] : ie[i - N_USERS * DIM];
  emb[i] = v; acc[i] = v;
}

__global__ void k_deg(const int* __restrict__ h, int* __restrict__ deg){
  int e = blockIdx.x * 256 + threadIdx.x;
  if (e < N_EDGES) atomicAdd(&deg[h[e]], 1);
}

__global__ void k_scan1(const int* __restrict__ deg, int* __restrict__ tmp,
                        int* __restrict__ aux){
  __shared__ int s[256];
  int t = threadIdx.x, i = blockIdx.x * 256 + t;
  int v = (i < N_NODES) ? deg[i] : 0;
  s[t] = v; __syncthreads();
  for (int off = 1; off < 256; off <<= 1){
    int x = (t >= off) ? s[t - off] : 0;
    __syncthreads();
    s[t] += x;
    __syncthreads();
  }
  if (i < N_NODES) tmp[i] = s[t];
  if (t == 255) aux[blockIdx.x] = s[255];
}

__global__ __launch_bounds__(1024) void k_scan2(int* __restrict__ aux, int n){
  __shared__ int s[1024];
  int t = threadIdx.x;
  int v = (t < n) ? aux[t] : 0;
  s[t] = v; __syncthreads();
  for (int off = 1; off < 1024; off <<= 1){
    int x = (t >= off) ? s[t - off] : 0;
    __syncthreads();
    s[t] += x;
    __syncthreads();
  }
  if (t < n) aux[t] = s[t] - v;   // exclusive
}

__global__ void k_rowptr(const int* __restrict__ tmp, const int* __restrict__ deg,
                         const int* __restrict__ aux, int* __restrict__ rp,
                         int* __restrict__ cur, float* __restrict__ dis,
                         int* __restrict__ curb){
  int i = blockIdx.x * 256 + threadIdx.x;
  if (i < N_NODES){
    int v = aux[i >> 8] + tmp[i] - deg[i];
    rp[i] = v; cur[i] = v;
    int d = deg[i];
    dis[i] = (d > 0) ? (1.f / sqrtf((float)d)) : 0.f;
    if ((i & 31) == 0) curb[i >> BSHIFT] = v;  // bucket append cursor = rp[b*32]
  }
  if (i == 0) rp[N_NODES] = N_EDGES;
}

// Scatter pass 1: append packed (h,t) to coarse bucket (32 rows/bucket).
// Active write frontier = NBUCK cache lines (~300 KB) -> merges in L2.
__global__ void k_scat1(const int* __restrict__ h, const int* __restrict__ t,
                        int* __restrict__ curb, unsigned long long* __restrict__ ht){
  int e = blockIdx.x * 256 + threadIdx.x;
  if (e >= N_EDGES) return;
  int hh = h[e];
  int pos = atomicAdd(&curb[hh >> BSHIFT], 1);
  ht[pos] = ((unsigned long long)(unsigned)hh << 32) | (unsigned)t[e];
}

// Scatter pass 2: bucket-grouped pairs -> exact CSR position. Concurrent
// writes land in a ~2.5 KB contiguous span per bucket -> merges in L2.
__global__ void k_scat2(const unsigned long long* __restrict__ ht,
                        int* __restrict__ cur, int* __restrict__ t_csr){
  int e = blockIdx.x * 256 + threadIdx.x;
  if (e >= N_EDGES) return;
  unsigned long long v = ht[e];
  int hh = (int)(v >> 32);
  int pos = atomicAdd(&cur[hh], 1);
  t_csr[pos] = (int)(unsigned)v;
}

// gnn[n] = dis[n] * sum_e dis[t_e] * emb[t_e]
// Slot layout: wave = 4 edge-slots x 16 lanes, lane covers 4 dims (float4).
__global__ void k_spmm_gnn(const int* __restrict__ rp, const int* __restrict__ t_csr,
                           const float* __restrict__ dis, const float* __restrict__ emb,
                           float* __restrict__ gnn, unsigned short* __restrict__ hgig_s){
  int w = (blockIdx.x * 256 + threadIdx.x) >> 6;
  int lane = threadIdx.x & 63;
  if (w >= N_NODES) return;
  int slot = lane >> 4, sub = lane & 15;
  int s = rp[w], e = rp[w + 1];
  float4 a = make_float4(0.f, 0.f, 0.f, 0.f);
  const float4* emb4 = (const float4*)emb;
  for (int i = s + slot; i < e; i += 4){
    int t = t_csr[i];
    float wt = dis[t];
    float4 ev = emb4[t * 16 + sub];
    a.x = fmaf(wt, ev.x, a.x);
    a.y = fmaf(wt, ev.y, a.y);
    a.z = fmaf(wt, ev.z, a.z);
    a.w = fmaf(wt, ev.w, a.w);
  }
#pragma unroll
  for (int m = 16; m <= 32; m <<= 1){
    a.x += __shfl_xor(a.x, m, 64);
    a.y += __shfl_xor(a.y, m, 64);
    a.z += __shfl_xor(a.z, m, 64);
    a.w += __shfl_xor(a.w, m, 64);
  }
  float dw = dis[w];
  float4 gv = make_float4(dw * a.x, dw * a.y, dw * a.z, dw * a.w);
  float sq = gv.x * gv.x + gv.y * gv.y + gv.z * gv.z + gv.w * gv.w;
  float nrm = row16_allsum(sq);
  float invn = 1.f / fmaxf(sqrtf(nrm), 1e-8f);
  if (slot == 0){
    ((float4*)gnn)[w * 16 + sub] = gv;
    int base = (w * DIM + 4 * sub) * 2;
    hgig_s[base]     = f2bf(gv.x * invn);
    hgig_s[base + 2] = f2bf(gv.y * invn);
    hgig_s[base + 4] = f2bf(gv.z * invn);
    hgig_s[base + 6] = f2bf(gv.w * invn);
  }
}

// out[n] = softmax(emb[n] @ W) @ W^T ; + inline L2-normalize -> high half of hgig
__global__ __launch_bounds__(256) void k_intent(const float* __restrict__ W,
                                                const float* __restrict__ emb,
                                                float* __restrict__ out,
                                                unsigned short* __restrict__ hgig_s,
                                                int base_node, int count){
  __shared__ float Wl[DIM * 129];
  __shared__ float el[4][DIM];
  __shared__ float pl[4][N_INTENTS];
  int tid = threadIdx.x;
  for (int i = tid; i < DIM * N_INTENTS; i += 256){
    int d = i >> 7, j = i & 127;
    Wl[d * 129 + j] = W[i];
  }
  __syncthreads();
  int wv = tid >> 6, lane = tid & 63;
  for (int base = blockIdx.x * 4; base < count; base += gridDim.x * 4){
    int n = base + wv;
    bool act = (n < count);
    if (act) el[wv][lane] = emb[(base_node + n) * DIM + lane];
    __syncthreads();
    float L0 = 0.f, L1 = 0.f;
    if (act){
#pragma unroll
      for (int d = 0; d < DIM; d++){
        float e = el[wv][d];
        L0 = fmaf(e, Wl[d * 129 + lane], L0);
        L1 = fmaf(e, Wl[d * 129 + lane + 64], L1);
      }
    }
    float m = wmax64(fmaxf(L0, L1));
    float p0 = __expf(L0 - m), p1 = __expf(L1 - m);
    float inv = 1.f / wsum64(p0 + p1);
    if (act){ pl[wv][lane] = p0; pl[wv][lane + 64] = p1; }
    __syncthreads();
    if (act){
      float o = 0.f;
#pragma unroll
      for (int j = 0; j < N_INTENTS; j++)
        o = fmaf(pl[wv][j], Wl[lane * 129 + j], o);
      float v = o * inv;
      int idx = (base_node + n) * DIM + lane;
      out[idx] = v;
      float nrm = wsum64(v * v);
      float invn = 1.f / fmaxf(sqrtf(nrm), 1e-8f);
      hgig_s[idx * 2 + 1] = f2bf(v * invn);
    }
    __syncthreads();
  }
}

// Fused adaptive passes + residual + acc.
// Slot layout: 4 edge-slots x 16 lanes x float4 dims; dual dot via DPP.
__global__ void k_adafuse(const int* __restrict__ rp, const int* __restrict__ t_csr,
                          const uint4* __restrict__ hgig4,
                          const float* __restrict__ inte, const float* __restrict__ emb,
                          float* __restrict__ gnn_io, float* __restrict__ acc){
  int w = (blockIdx.x * 256 + threadIdx.x) >> 6;
  int lane = threadIdx.x & 63;
  if (w >= N_NODES) return;
  int slot = lane >> 4, sub = lane & 15;
  uint4 hp = hgig4[w * 16 + sub];
  float hg0 = bf_lo(hp.x), hg1 = bf_lo(hp.y), hg2 = bf_lo(hp.z), hg3 = bf_lo(hp.w);
  float hi0 = bf_hi(hp.x), hi1 = bf_hi(hp.y), hi2 = bf_hi(hp.z), hi3 = bf_hi(hp.w);
  int s = rp[w], e = rp[w + 1];
  const float4* emb4 = (const float4*)emb;
  float4 s1 = make_float4(0.f, 0.f, 0.f, 0.f);
  float4 s2 = make_float4(0.f, 0.f, 0.f, 0.f);
  float r1 = 0.f, r2 = 0.f;
  for (int i = s + slot; i < e; i += 4){
    int t = t_csr[i];
    uint4 tp = hgig4[t * 16 + sub];
    float4 ev = emb4[t * 16 + sub];
    float p = hg0 * bf_lo(tp.x) + hg1 * bf_lo(tp.y)
            + hg2 * bf_lo(tp.z) + hg3 * bf_lo(tp.w);
    float q = hi0 * bf_hi(tp.x) + hi1 * bf_hi(tp.y)
            + hi2 * bf_hi(tp.z) + hi3 * bf_hi(tp.w);
    p = row16_allsum(p);
    q = row16_allsum(q);
    float a1 = fmaf(p, 0.5f, 0.5f);
    float a2 = fmaf(q, 0.5f, 0.5f);
    r1 += a1; r2 += a2;
    s1.x = fmaf(a1, ev.x, s1.x); s1.y = fmaf(a1, ev.y, s1.y);
    s1.z = fmaf(a1, ev.z, s1.z); s1.w = fmaf(a1, ev.w, s1.w);
    s2.x = fmaf(a2, ev.x, s2.x); s2.y = fmaf(a2, ev.y, s2.y);
    s2.z = fmaf(a2, ev.z, s2.z); s2.w = fmaf(a2, ev.w, s2.w);
  }
#pragma unroll
  for (int m = 16; m <= 32; m <<= 1){
    s1.x += __shfl_xor(s1.x, m, 64); s1.y += __shfl_xor(s1.y, m, 64);
    s1.z += __shfl_xor(s1.z, m, 64); s1.w += __shfl_xor(s1.w, m, 64);
    s2.x += __shfl_xor(s2.x, m, 64); s2.y += __shfl_xor(s2.y, m, 64);
    s2.z += __shfl_xor(s2.z, m, 64); s2.w += __shfl_xor(s2.w, m, 64);
    r1   += __shfl_xor(r1,   m, 64); r2   += __shfl_xor(r2,   m, 64);
  }
  float d1 = (r1 > 0.f) ? 1.f / r1 : 0.f;
  float d2 = (r2 > 0.f) ? 1.f / r2 : 0.f;
  if (slot == 0){
    int idx4 = w * 16 + sub;
    float4 g = ((float4*)gnn_io)[idx4];
    float4 it = ((const float4*)inte)[idx4];
    float4 em = emb4[idx4];
    float4 nv;
    nv.x = g.x + it.x + em.x + d1 * s1.x + d2 * s2.x;
    nv.y = g.y + it.y + em.y + d1 * s1.y + d2 * s2.y;
    nv.z = g.z + it.z + em.z + d1 * s1.z + d2 * s2.z;
    nv.w = g.w + it.w + em.w + d1 * s1.w + d2 * s2.w;
    ((float4*)gnn_io)[idx4] = nv;
    float4 ac = ((float4*)acc)[idx4];
    ac.x += nv.x; ac.y += nv.y; ac.z += nv.z; ac.w += nv.w;
    ((float4*)acc)[idx4] = ac;
  }
}

extern "C" void kernel_launch(void* const* d_in, const int* in_sizes, int n_in,
                              void* d_out, int out_size, void* d_ws, size_t ws_size,
                              hipStream_t stream){
  const float* ue = (const float*)d_in[0];
  const float* ie = (const float*)d_in[1];
  const float* wu = (const float*)d_in[2];
  const float* wi = (const float*)d_in[3];
  const int* all_h = (const int*)d_in[4];
  const int* all_t = (const int*)d_in[5];
  float* acc = (float*)d_out;

  char* p = (char*)d_ws;
  auto take = [&](size_t bytes)->char*{
    char* r = p; p += (bytes + 255) & ~size_t(255); return r;
  };
  float*  embA  = (float*)take(sizeof(float) * N_NODES * DIM);
  float*  embB  = (float*)take(sizeof(float) * N_NODES * DIM);
  float*  inte  = (float*)take(sizeof(float) * N_NODES * DIM);
  unsigned int* hgig = (unsigned int*)take(sizeof(unsigned int) * N_NODES * DIM);
  int*    t_csr = (int*)take(sizeof(int) * N_EDGES);
  float*  dis   = (float*)take(sizeof(float) * N_NODES);
  int*    deg   = (int*)take(sizeof(int) * N_NODES);
  int*    tmp   = (int*)take(sizeof(int) * N_NODES);
  int*    aux   = (int*)take(sizeof(int) * 1024);
  int*    rp    = (int*)take(sizeof(int) * (N_NODES + 1));
  int*    cur   = (int*)take(sizeof(int) * N_NODES);
  int*    curb  = (int*)take(sizeof(int) * NBUCK);
  if ((size_t)(p - (char*)d_ws) > ws_size) return;
  // ht staging (24 MB) aliases hgig (38.4 MB): only live before the layer loop
  unsigned long long* ht = (unsigned long long*)hgig;

  const int ELEM_B  = (N_NODES * DIM + 255) / 256;
  const int NODEW_B = (N_NODES * 64 + 255) / 256;
  const int EDGE_B  = (N_EDGES + 255) / 256;
  const int NODE_B  = (N_NODES + 255) / 256;

  hipMemsetAsync(deg, 0, sizeof(int) * N_NODES, stream);
  k_init<<<ELEM_B, 256, 0, stream>>>(ue, ie, embA, acc);
  k_deg<<<EDGE_B, 256, 0, stream>>>(all_h, deg);
  k_scan1<<<NODE_B, 256, 0, stream>>>(deg, tmp, aux);
  k_scan2<<<1, 1024, 0, stream>>>(aux, NODE_B);
  k_rowptr<<<NODE_B, 256, 0, stream>>>(tmp, deg, aux, rp, cur, dis, curb);
  k_scat1<<<EDGE_B, 256, 0, stream>>>(all_h, all_t, curb, ht);
  k_scat2<<<EDGE_B, 256, 0, stream>>>(ht, cur, t_csr);

  float* eA = embA;
  float* eB = embB;
  for (int layer = 0; layer < 2; layer++){
    k_spmm_gnn<<<NODEW_B, 256, 0, stream>>>(rp, t_csr, dis, eA, eB,
                                            (unsigned short*)hgig);
    k_intent<<<(N_USERS + 3) / 4, 256, 0, stream>>>(wu, eA, inte,
                                                    (unsigned short*)hgig, 0, N_USERS);
    k_intent<<<(N_ITEMS + 3) / 4, 256, 0, stream>>>(wi, eA, inte,
                                                    (unsigned short*)hgig, N_USERS, N_ITEMS);
    k_adafuse<<<NODEW_B, 256, 0, stream>>>(rp, t_csr, (const uint4*)hgig,
                                           inte, eA, eB, acc);
    float* t = eA; eA = eB; eB = t;
  }
}

// Round 6
// 1577.535 us; speedup vs baseline: 1.1248x; 1.1248x over previous
//
#include <hip/hip_runtime.h>
#include <hip/hip_bf16.h>

#define N_USERS   50000
#define N_ITEMS   100000
#define N_NODES   150000
#define DIM       64
#define N_INTENTS 128
#define N_EDGES   3000000

static __device__ __forceinline__ float wsum64(float v){
#pragma unroll
  for (int m = 32; m >= 1; m >>= 1) v += __shfl_xor(v, m, 64);
  return v;
}
static __device__ __forceinline__ float wmax64(float v){
#pragma unroll
  for (int m = 32; m >= 1; m >>= 1) v = fmaxf(v, __shfl_xor(v, m, 64));
  return v;
}

// ---- DPP 16-lane row reduction (full-rate VALU)
template<int CTRL>
static __device__ __forceinline__ float dpp_ror_add(float x){
  int t = __builtin_amdgcn_update_dpp(0, __builtin_bit_cast(int, x),
                                      CTRL, 0xF, 0xF, true);
  return x + __builtin_bit_cast(float, t);
}
static __device__ __forceinline__ float row16_allsum(float x){
  x = dpp_ror_add<0x128>(x);  // row_ror:8
  x = dpp_ror_add<0x124>(x);  // row_ror:4
  x = dpp_ror_add<0x122>(x);  // row_ror:2
  x = dpp_ror_add<0x121>(x);  // row_ror:1
  return x;
}

// bf16 pack/unpack
static __device__ __forceinline__ unsigned short f2bf(float x){
  __hip_bfloat16 h = __float2bfloat16(x);
  return __builtin_bit_cast(unsigned short, h);
}
static __device__ __forceinline__ float bf_lo(unsigned int v){
  return __builtin_bit_cast(float, v << 16);
}
static __device__ __forceinline__ float bf_hi(unsigned int v){
  return __builtin_bit_cast(float, v & 0xFFFF0000u);
}

// emb = concat(user_emb, item_emb); acc(=d_out) = emb; embb = bf16(emb)
__global__ void k_init(const float* __restrict__ ue, const float* __restrict__ ie,
                       float* __restrict__ emb, float* __restrict__ acc,
                       unsigned short* __restrict__ embb){
  int i = blockIdx.x * 256 + threadIdx.x;
  if (i >= N_NODES * DIM) return;
  float v = (i < N_USERS * DIM) ? ue[i] : ie[i - N_USERS * DIM];
  emb[i] = v; acc[i] = v; embb[i] = f2bf(v);
}

__global__ void k_deg(const int* __restrict__ h, int* __restrict__ deg){
  int e = blockIdx.x * 256 + threadIdx.x;
  if (e < N_EDGES) atomicAdd(&deg[h[e]], 1);
}

__global__ void k_scan1(const int* __restrict__ deg, int* __restrict__ tmp,
                        int* __restrict__ aux){
  __shared__ int s[256];
  int t = threadIdx.x, i = blockIdx.x * 256 + t;
  int v = (i < N_NODES) ? deg[i] : 0;
  s[t] = v; __syncthreads();
  for (int off = 1; off < 256; off <<= 1){
    int x = (t >= off) ? s[t - off] : 0;
    __syncthreads();
    s[t] += x;
    __syncthreads();
  }
  if (i < N_NODES) tmp[i] = s[t];
  if (t == 255) aux[blockIdx.x] = s[255];
}

__global__ __launch_bounds__(1024) void k_scan2(int* __restrict__ aux, int n){
  __shared__ int s[1024];
  int t = threadIdx.x;
  int v = (t < n) ? aux[t] : 0;
  s[t] = v; __syncthreads();
  for (int off = 1; off < 1024; off <<= 1){
    int x = (t >= off) ? s[t - off] : 0;
    __syncthreads();
    s[t] += x;
    __syncthreads();
  }
  if (t < n) aux[t] = s[t] - v;   // exclusive
}

__global__ void k_rowptr(const int* __restrict__ tmp, const int* __restrict__ deg,
                         const int* __restrict__ aux, int* __restrict__ rp,
                         int* __restrict__ cur, float* __restrict__ dis){
  int i = blockIdx.x * 256 + threadIdx.x;
  if (i < N_NODES){
    int v = aux[i >> 8] + tmp[i] - deg[i];
    rp[i] = v; cur[i] = v;
    int d = deg[i];
    dis[i] = (d > 0) ? (1.f / sqrtf((float)d)) : 0.f;
  }
  if (i == 0) rp[N_NODES] = N_EDGES;
}

// single-pass CSR scatter (two-level bucket version regressed: bucket-counter
// atomic serialization > write-amp savings — measured r5: +70us net)
__global__ void k_scatter(const int* __restrict__ h, const int* __restrict__ t,
                          int* __restrict__ cur, int* __restrict__ t_csr){
  int e = blockIdx.x * 256 + threadIdx.x;
  if (e >= N_EDGES) return;
  int pos = atomicAdd(&cur[h[e]], 1);
  t_csr[pos] = t[e];
}

// gnn[n] = dis[n] * sum_e dis[t_e] * emb[t_e], gathering bf16 embb (128B/edge)
// Slot layout: wave = 4 edge-slots x 16 lanes, lane covers 4 dims.
__global__ void k_spmm_gnn(const int* __restrict__ rp, const int* __restrict__ t_csr,
                           const float* __restrict__ dis,
                           const uint2* __restrict__ embb2,
                           float* __restrict__ gnn, unsigned short* __restrict__ hgig_s){
  int w = (blockIdx.x * 256 + threadIdx.x) >> 6;
  int lane = threadIdx.x & 63;
  if (w >= N_NODES) return;
  int slot = lane >> 4, sub = lane & 15;
  int s = rp[w], e = rp[w + 1];
  float4 a = make_float4(0.f, 0.f, 0.f, 0.f);
  for (int i = s + slot; i < e; i += 4){
    int t = t_csr[i];
    float wt = dis[t];                    // 600KB table: L2-resident
    uint2 ev = embb2[t * 16 + sub];       // 4 bf16 dims
    a.x = fmaf(wt, bf_lo(ev.x), a.x);
    a.y = fmaf(wt, bf_hi(ev.x), a.y);
    a.z = fmaf(wt, bf_lo(ev.y), a.z);
    a.w = fmaf(wt, bf_hi(ev.y), a.w);
  }
#pragma unroll
  for (int m = 16; m <= 32; m <<= 1){
    a.x += __shfl_xor(a.x, m, 64);
    a.y += __shfl_xor(a.y, m, 64);
    a.z += __shfl_xor(a.z, m, 64);
    a.w += __shfl_xor(a.w, m, 64);
  }
  float dw = dis[w];
  float4 gv = make_float4(dw * a.x, dw * a.y, dw * a.z, dw * a.w);
  float sq = gv.x * gv.x + gv.y * gv.y + gv.z * gv.z + gv.w * gv.w;
  float nrm = row16_allsum(sq);
  float invn = 1.f / fmaxf(sqrtf(nrm), 1e-8f);
  if (slot == 0){
    ((float4*)gnn)[w * 16 + sub] = gv;
    int base = (w * DIM + 4 * sub) * 2;
    hgig_s[base]     = f2bf(gv.x * invn);
    hgig_s[base + 2] = f2bf(gv.y * invn);
    hgig_s[base + 4] = f2bf(gv.z * invn);
    hgig_s[base + 6] = f2bf(gv.w * invn);
  }
}

// out(bf16)[n] = softmax(emb[n] @ W) @ W^T ; + L2-normalize -> high half of hgig
__global__ __launch_bounds__(256) void k_intent(const float* __restrict__ W,
                                                const float* __restrict__ emb,
                                                unsigned short* __restrict__ out_bf,
                                                unsigned short* __restrict__ hgig_s,
                                                int base_node, int count){
  __shared__ float Wl[DIM * 129];
  __shared__ float el[4][DIM];
  __shared__ float pl[4][N_INTENTS];
  int tid = threadIdx.x;
  for (int i = tid; i < DIM * N_INTENTS; i += 256){
    int d = i >> 7, j = i & 127;
    Wl[d * 129 + j] = W[i];
  }
  __syncthreads();
  int wv = tid >> 6, lane = tid & 63;
  for (int base = blockIdx.x * 4; base < count; base += gridDim.x * 4){
    int n = base + wv;
    bool act = (n < count);
    if (act) el[wv][lane] = emb[(base_node + n) * DIM + lane];
    __syncthreads();
    float L0 = 0.f, L1 = 0.f;
    if (act){
#pragma unroll
      for (int d = 0; d < DIM; d++){
        float e = el[wv][d];
        L0 = fmaf(e, Wl[d * 129 + lane], L0);
        L1 = fmaf(e, Wl[d * 129 + lane + 64], L1);
      }
    }
    float m = wmax64(fmaxf(L0, L1));
    float p0 = __expf(L0 - m), p1 = __expf(L1 - m);
    float inv = 1.f / wsum64(p0 + p1);
    if (act){ pl[wv][lane] = p0; pl[wv][lane + 64] = p1; }
    __syncthreads();
    if (act){
      float o = 0.f;
#pragma unroll
      for (int j = 0; j < N_INTENTS; j++)
        o = fmaf(pl[wv][j], Wl[lane * 129 + j], o);
      float v = o * inv;
      int idx = (base_node + n) * DIM + lane;
      out_bf[idx] = f2bf(v);
      float nrm = wsum64(v * v);
      float invn = 1.f / fmaxf(sqrtf(nrm), 1e-8f);
      hgig_s[idx * 2 + 1] = f2bf(v * invn);
    }
    __syncthreads();
  }
}

// Fused adaptive passes + residual + acc.
// Per edge per lane: uint4 hgig (16B) + uint2 embb (8B) -> 384B/edge total.
__global__ void k_adafuse(const int* __restrict__ rp, const int* __restrict__ t_csr,
                          const uint4* __restrict__ hgig4,
                          const uint2* __restrict__ inte_bf2,
                          const uint2* __restrict__ embb2,
                          const float* __restrict__ emb,
                          float* __restrict__ gnn_io, float* __restrict__ acc){
  int w = (blockIdx.x * 256 + threadIdx.x) >> 6;
  int lane = threadIdx.x & 63;
  if (w >= N_NODES) return;
  int slot = lane >> 4, sub = lane & 15;
  uint4 hp = hgig4[w * 16 + sub];
  float hg0 = bf_lo(hp.x), hg1 = bf_lo(hp.y), hg2 = bf_lo(hp.z), hg3 = bf_lo(hp.w);
  float hi0 = bf_hi(hp.x), hi1 = bf_hi(hp.y), hi2 = bf_hi(hp.z), hi3 = bf_hi(hp.w);
  int s = rp[w], e = rp[w + 1];
  float4 s1 = make_float4(0.f, 0.f, 0.f, 0.f);
  float4 s2 = make_float4(0.f, 0.f, 0.f, 0.f);
  float r1 = 0.f, r2 = 0.f;
  for (int i = s + slot; i < e; i += 4){
    int t = t_csr[i];
    uint4 tp = hgig4[t * 16 + sub];
    uint2 ev = embb2[t * 16 + sub];
    float p = hg0 * bf_lo(tp.x) + hg1 * bf_lo(tp.y)
            + hg2 * bf_lo(tp.z) + hg3 * bf_lo(tp.w);
    float q = hi0 * bf_hi(tp.x) + hi1 * bf_hi(tp.y)
            + hi2 * bf_hi(tp.z) + hi3 * bf_hi(tp.w);
    p = row16_allsum(p);
    q = row16_allsum(q);
    float a1 = fmaf(p, 0.5f, 0.5f);
    float a2 = fmaf(q, 0.5f, 0.5f);
    r1 += a1; r2 += a2;
    float v0 = bf_lo(ev.x), v1 = bf_hi(ev.x), v2 = bf_lo(ev.y), v3 = bf_hi(ev.y);
    s1.x = fmaf(a1, v0, s1.x); s1.y = fmaf(a1, v1, s1.y);
    s1.z = fmaf(a1, v2, s1.z); s1.w = fmaf(a1, v3, s1.w);
    s2.x = fmaf(a2, v0, s2.x); s2.y = fmaf(a2, v1, s2.y);
    s2.z = fmaf(a2, v2, s2.z); s2.w = fmaf(a2, v3, s2.w);
  }
#pragma unroll
  for (int m = 16; m <= 32; m <<= 1){
    s1.x += __shfl_xor(s1.x, m, 64); s1.y += __shfl_xor(s1.y, m, 64);
    s1.z += __shfl_xor(s1.z, m, 64); s1.w += __shfl_xor(s1.w, m, 64);
    s2.x += __shfl_xor(s2.x, m, 64); s2.y += __shfl_xor(s2.y, m, 64);
    s2.z += __shfl_xor(s2.z, m, 64); s2.w += __shfl_xor(s2.w, m, 64);
    r1   += __shfl_xor(r1,   m, 64); r2   += __shfl_xor(r2,   m, 64);
  }
  float d1 = (r1 > 0.f) ? 1.f / r1 : 0.f;
  float d2 = (r2 > 0.f) ? 1.f / r2 : 0.f;
  if (slot == 0){
    int idx4 = w * 16 + sub;
    float4 g = ((float4*)gnn_io)[idx4];
    uint2 it = inte_bf2[idx4];
    float4 em = ((const float4*)emb)[idx4];
    float4 nv;
    nv.x = g.x + bf_lo(it.x) + em.x + d1 * s1.x + d2 * s2.x;
    nv.y = g.y + bf_hi(it.x) + em.y + d1 * s1.y + d2 * s2.y;
    nv.z = g.z + bf_lo(it.y) + em.z + d1 * s1.z + d2 * s2.z;
    nv.w = g.w + bf_hi(it.y) + em.w + d1 * s1.w + d2 * s2.w;
    ((float4*)gnn_io)[idx4] = nv;
    float4 ac = ((float4*)acc)[idx4];
    ac.x += nv.x; ac.y += nv.y; ac.z += nv.z; ac.w += nv.w;
    ((float4*)acc)[idx4] = ac;
  }
}

// embb = bf16(new emb) for the next layer (runs after adafuse -> no race)
__global__ void k_conv(const float* __restrict__ emb, unsigned short* __restrict__ embb){
  int i = blockIdx.x * 256 + threadIdx.x;
  if (i < N_NODES * DIM) embb[i] = f2bf(emb[i]);
}

extern "C" void kernel_launch(void* const* d_in, const int* in_sizes, int n_in,
                              void* d_out, int out_size, void* d_ws, size_t ws_size,
                              hipStream_t stream){
  const float* ue = (const float*)d_in[0];
  const float* ie = (const float*)d_in[1];
  const float* wu = (const float*)d_in[2];
  const float* wi = (const float*)d_in[3];
  const int* all_h = (const int*)d_in[4];
  const int* all_t = (const int*)d_in[5];
  float* acc = (float*)d_out;

  char* p = (char*)d_ws;
  auto take = [&](size_t bytes)->char*{
    char* r = p; p += (bytes + 255) & ~size_t(255); return r;
  };
  float*  embA  = (float*)take(sizeof(float) * N_NODES * DIM);
  float*  embB  = (float*)take(sizeof(float) * N_NODES * DIM);
  unsigned int* hgig = (unsigned int*)take(sizeof(unsigned int) * N_NODES * DIM);
  unsigned short* inte_bf = (unsigned short*)take(sizeof(short) * N_NODES * DIM);
  unsigned short* embb    = (unsigned short*)take(sizeof(short) * N_NODES * DIM);
  int*    t_csr = (int*)take(sizeof(int) * N_EDGES);
  float*  dis   = (float*)take(sizeof(float) * N_NODES);
  int*    deg   = (int*)take(sizeof(int) * N_NODES);
  int*    tmp   = (int*)take(sizeof(int) * N_NODES);
  int*    aux   = (int*)take(sizeof(int) * 1024);
  int*    rp    = (int*)take(sizeof(int) * (N_NODES + 1));
  int*    cur   = (int*)take(sizeof(int) * N_NODES);
  if ((size_t)(p - (char*)d_ws) > ws_size) return;

  const int ELEM_B  = (N_NODES * DIM + 255) / 256;
  const int NODEW_B = (N_NODES * 64 + 255) / 256;
  const int EDGE_B  = (N_EDGES + 255) / 256;
  const int NODE_B  = (N_NODES + 255) / 256;

  hipMemsetAsync(deg, 0, sizeof(int) * N_NODES, stream);
  k_init<<<ELEM_B, 256, 0, stream>>>(ue, ie, embA, acc, embb);
  k_deg<<<EDGE_B, 256, 0, stream>>>(all_h, deg);
  k_scan1<<<NODE_B, 256, 0, stream>>>(deg, tmp, aux);
  k_scan2<<<1, 1024, 0, stream>>>(aux, NODE_B);
  k_rowptr<<<NODE_B, 256, 0, stream>>>(tmp, deg, aux, rp, cur, dis);
  k_scatter<<<EDGE_B, 256, 0, stream>>>(all_h, all_t, cur, t_csr);

  float* eA = embA;
  float* eB = embB;
  for (int layer = 0; layer < 2; layer++){
    k_spmm_gnn<<<NODEW_B, 256, 0, stream>>>(rp, t_csr, dis, (const uint2*)embb,
                                            eB, (unsigned short*)hgig);
    k_intent<<<(N_USERS + 3) / 4, 256, 0, stream>>>(wu, eA, inte_bf,
                                                    (unsigned short*)hgig, 0, N_USERS);
    k_intent<<<(N_ITEMS + 3) / 4, 256, 0, stream>>>(wi, eA, inte_bf,
                                                    (unsigned short*)hgig, N_USERS, N_ITEMS);
    k_adafuse<<<NODEW_B, 256, 0, stream>>>(rp, t_csr, (const uint4*)hgig,
                                           (const uint2*)inte_bf, (const uint2*)embb,
                                           eA, eB, acc);
    if (layer == 0)
      k_conv<<<ELEM_B, 256, 0, stream>>>(eB, embb);
    float* t = eA; eA = eB; eB = t;
  }
}